// Round 8
// baseline (1468.384 us; speedup 1.0000x reference)
//
#include <hip/hip_runtime.h>
#include <hip/hip_bf16.h>
#include <cstdint>
#include <cstddef>

#define B_ 16384
#define F_ 4096
#define P_ 32
#define D_ 128
#define BLOCKS 512     // grid; 16 blocks per partition
#define WPB 8          // waves per block (512 threads)
#define ITERS 8        // tiles of 16 rows per wave: 16*8*8*16 blocks = 16384 rows

using f32x4 = __attribute__((ext_vector_type(4))) float;
using s16x8 = __attribute__((ext_vector_type(8))) short;

union abuf { s16x8 v; uint32_t u[4]; };

__device__ inline uint32_t pk_bf16(float a, float b) {
    float2 f; f.x = a; f.y = b;
    union { __hip_bfloat162 h; uint32_t u; } cv;
    cv.h = __float22bfloat162_rn(f);
    return cv.u;
}
// tanh(z) = 1 - 2/(e^{2z}+1); caller passes ze = 2*log2(e)*z (folded into BN)
__device__ inline float tanh_e(float ze) {
    float e = __builtin_amdgcn_exp2f(ze);
    return 1.f - 2.f * __builtin_amdgcn_rcpf(e + 1.f);
}

// Stage W[p] (128x128 f32, row-major [k][c]) into LDS as MFMA A-operand
// fragments with k-permutation k(sp,l4,t) = sp*32 + (t>=4)*16 + l4*4 + (t&3).
// Matches a B-operand built from f32x4 loads at cols j*16 + l4*4, so the
// loaded x tile doubles as the residual. Wave read for (j,sp) = contiguous
// 1KB (lane*16) -> conflict-free ds_read_b128 (verified: 0 conflicts).
// 512-thread version: 2048 slots, 4 rounds.
__device__ inline void stage_wp(const float* __restrict__ Wp, short* s_w, int tid) {
#pragma unroll
    for (int it = 0; it < 4; ++it) {
        int slot = it * 512 + tid;
        int l15 = slot & 15;
        int l4  = (slot >> 4) & 3;
        int sp  = (slot >> 6) & 3;
        int j   = slot >> 8;
        const float* s0 = Wp + (size_t)(sp * 32 + l4 * 4) * D_ + j * 16 + l15;
        const float* s1 = s0 + (size_t)16 * D_;
        abuf a;
        a.u[0] = pk_bf16(s0[0],            s0[(size_t)D_]);
        a.u[1] = pk_bf16(s0[(size_t)2*D_], s0[(size_t)3*D_]);
        a.u[2] = pk_bf16(s1[0],            s1[(size_t)D_]);
        a.u[3] = pk_bf16(s1[(size_t)2*D_], s1[(size_t)3*D_]);
        *(s16x8*)((char*)s_w + (size_t)slot * 16) = a.v;
    }
}

// ---- K1: stats of y1 = x @ BD(W1); y1 lives only in registers -------------
__global__ __launch_bounds__(512, 4) void k_stats1(
    const float* __restrict__ x, const float* __restrict__ W1,
    float* __restrict__ gsum, float* __restrict__ gsq)
{
    __shared__ short s_w[D_ * D_];
    __shared__ float s_sum[D_], s_sq[D_];
    const int tid = threadIdx.x;
    const int p = blockIdx.x >> 4, strip = blockIdx.x & 15;
    stage_wp(W1 + (size_t)p * D_ * D_, s_w, tid);
    if (tid < D_) { s_sum[tid] = 0.f; s_sq[tid] = 0.f; }
    __syncthreads();
    const int wave = tid >> 6, lane = tid & 63;
    const int l15 = lane & 15, l4 = lane >> 4;
    const int ldsb = lane * 16;

    f32x4 csum[8], csq[8];
#pragma unroll
    for (int j = 0; j < 8; ++j) { csum[j] = (f32x4){0,0,0,0}; csq[j] = (f32x4){0,0,0,0}; }

    auto LOADX = [&](f32x4 (&xv)[8], int it) {
        const int g = strip * 64 + it * 8 + wave;
        const float* ap = x + (size_t)(g * 16 + l15) * F_ + p * D_ + l4 * 4;
#pragma unroll
        for (int j = 0; j < 8; ++j)
            xv[j] = *(const f32x4*)(ap + j * 16);
    };

    auto TILE = [&](f32x4 (&xv)[8]) {
        abuf a[4];
#pragma unroll
        for (int s = 0; s < 4; ++s) {
            a[s].u[0] = pk_bf16(xv[2*s][0],   xv[2*s][1]);
            a[s].u[1] = pk_bf16(xv[2*s][2],   xv[2*s][3]);
            a[s].u[2] = pk_bf16(xv[2*s+1][0], xv[2*s+1][1]);
            a[s].u[3] = pk_bf16(xv[2*s+1][2], xv[2*s+1][3]);
        }
        f32x4 acc[8];
#pragma unroll
        for (int j = 0; j < 8; ++j) acc[j] = (f32x4){0,0,0,0};
#pragma unroll
        for (int s = 0; s < 4; ++s)
#pragma unroll
            for (int j = 0; j < 8; ++j) {
                s16x8 w = *(const s16x8*)((const char*)s_w + (j * 4 + s) * 1024 + ldsb);
                acc[j] = __builtin_amdgcn_mfma_f32_16x16x32_bf16(w, a[s].v, acc[j], 0, 0, 0);
            }
#pragma unroll
        for (int j = 0; j < 8; ++j)
#pragma unroll
            for (int r = 0; r < 4; ++r) {
                float v = acc[j][r];
                csum[j][r] += v;
                csq[j][r] = fmaf(v, v, csq[j][r]);
            }
    };

    f32x4 xv0[8], xv1[8];
    LOADX(xv0, 0);
#pragma unroll
    for (int h = 0; h < 4; ++h) {
        LOADX(xv1, 2 * h + 1);
        TILE(xv0);
        if (h < 3) LOADX(xv0, 2 * h + 2);
        TILE(xv1);
    }

#pragma unroll
    for (int j = 0; j < 8; ++j)
#pragma unroll
        for (int r = 0; r < 4; ++r) {
            float sm = csum[j][r], q = csq[j][r];
            sm += __shfl_xor(sm, 1); q += __shfl_xor(q, 1);
            sm += __shfl_xor(sm, 2); q += __shfl_xor(q, 2);
            sm += __shfl_xor(sm, 4); q += __shfl_xor(q, 4);
            sm += __shfl_xor(sm, 8); q += __shfl_xor(q, 8);
            if (l15 == 0) {
                atomicAdd(&s_sum[j * 16 + l4 * 4 + r], sm);
                atomicAdd(&s_sq [j * 16 + l4 * 4 + r], q);
            }
        }
    __syncthreads();
    if (tid < D_) {
        atomicAdd(&gsum[p * D_ + tid], s_sum[tid]);
        atomicAdd(&gsq [p * D_ + tid], s_sq[tid]);
    }
}

// ---- K2/K3: recompute y1 -> tanh(bn1) -> GEMM2 -> + x = y3 ----------------
// OUT=false: accumulate column stats of y3, store NOTHING.
// OUT=true : apply bn3+tanh and write o3 (f32) straight to d_out.
template<bool OUT>
__global__ __launch_bounds__(512, 4) void k_pass(
    const float* __restrict__ x, float* __restrict__ out,
    const float* __restrict__ W1, const float* __restrict__ W2,
    const float* __restrict__ sce1, const float* __restrict__ she1,
    const float* __restrict__ sce3, const float* __restrict__ she3,
    float* __restrict__ gsum, float* __restrict__ gsq)
{
    __shared__ short s_w1[D_ * D_];
    __shared__ short s_w2[D_ * D_];
    __shared__ float s_sc1[D_], s_sh1[D_];
    __shared__ float s_a[D_], s_b[D_];   // OUT: sc3/sh3;  !OUT: sum/sq
    const int tid = threadIdx.x;
    const int p = blockIdx.x >> 4, strip = blockIdx.x & 15;
    stage_wp(W1 + (size_t)p * D_ * D_, s_w1, tid);
    stage_wp(W2 + (size_t)p * D_ * D_, s_w2, tid);
    if (tid < D_) {
        s_sc1[tid] = sce1[p * D_ + tid];
        s_sh1[tid] = she1[p * D_ + tid];
        if (OUT) {
            s_a[tid] = sce3[p * D_ + tid];
            s_b[tid] = she3[p * D_ + tid];
        } else {
            s_a[tid] = 0.f; s_b[tid] = 0.f;
        }
    }
    __syncthreads();
    const int wave = tid >> 6, lane = tid & 63;
    const int l15 = lane & 15, l4 = lane >> 4;
    const int ldsb = lane * 16;

    f32x4 csum[8], csq[8];
    if (!OUT) {
#pragma unroll
        for (int j = 0; j < 8; ++j) { csum[j] = (f32x4){0,0,0,0}; csq[j] = (f32x4){0,0,0,0}; }
    }

    auto LOADX = [&](f32x4 (&xv)[8], int it) {
        const int g = strip * 64 + it * 8 + wave;
        const float* ap = x + (size_t)(g * 16 + l15) * F_ + p * D_ + l4 * 4;
#pragma unroll
        for (int j = 0; j < 8; ++j)
            xv[j] = *(const f32x4*)(ap + j * 16);
    };

    auto TILE = [&](f32x4 (&xv)[8], int it) {
        // ---- GEMM1 recompute ----
        abuf a[4];
#pragma unroll
        for (int s = 0; s < 4; ++s) {
            a[s].u[0] = pk_bf16(xv[2*s][0],   xv[2*s][1]);
            a[s].u[1] = pk_bf16(xv[2*s][2],   xv[2*s][3]);
            a[s].u[2] = pk_bf16(xv[2*s+1][0], xv[2*s+1][1]);
            a[s].u[3] = pk_bf16(xv[2*s+1][2], xv[2*s+1][3]);
        }
        f32x4 acc[8];
#pragma unroll
        for (int j = 0; j < 8; ++j) acc[j] = (f32x4){0,0,0,0};
#pragma unroll
        for (int s = 0; s < 4; ++s)
#pragma unroll
            for (int j = 0; j < 8; ++j) {
                s16x8 w = *(const s16x8*)((const char*)s_w1 + (j * 4 + s) * 1024 + ldsb);
                acc[j] = __builtin_amdgcn_mfma_f32_16x16x32_bf16(w, a[s].v, acc[j], 0, 0, 0);
            }
        // ---- bn1 + tanh -> B-fragments for GEMM2 ----
#pragma unroll
        for (int sp = 0; sp < 4; ++sp) {
            const int kb = sp * 32 + l4 * 4;
            f32x4 sc0 = *(const f32x4*)&s_sc1[kb], sc1 = *(const f32x4*)&s_sc1[kb + 16];
            f32x4 sh0 = *(const f32x4*)&s_sh1[kb], sh1 = *(const f32x4*)&s_sh1[kb + 16];
            float t0[4], t1[4];
#pragma unroll
            for (int q = 0; q < 4; ++q) {
                t0[q] = tanh_e(fmaf(acc[2*sp][q],   sc0[q], sh0[q]));
                t1[q] = tanh_e(fmaf(acc[2*sp+1][q], sc1[q], sh1[q]));
            }
            a[sp].u[0] = pk_bf16(t0[0], t0[1]);
            a[sp].u[1] = pk_bf16(t0[2], t0[3]);
            a[sp].u[2] = pk_bf16(t1[0], t1[1]);
            a[sp].u[3] = pk_bf16(t1[2], t1[3]);
        }
        // ---- GEMM2 ----
#pragma unroll
        for (int j = 0; j < 8; ++j) acc[j] = (f32x4){0,0,0,0};
#pragma unroll
        for (int sp = 0; sp < 4; ++sp)
#pragma unroll
            for (int j = 0; j < 8; ++j) {
                s16x8 w = *(const s16x8*)((const char*)s_w2 + (j * 4 + sp) * 1024 + ldsb);
                acc[j] = __builtin_amdgcn_mfma_f32_16x16x32_bf16(w, a[sp].v, acc[j], 0, 0, 0);
            }
        // ---- y3 = acc + x (residual from the SAME registers) ----
        if (OUT) {
            const int g = strip * 64 + it * 8 + wave;
            float* rp = out + (size_t)(g * 16 + l15) * F_ + p * D_ + l4 * 4;
#pragma unroll
            for (int j = 0; j < 8; ++j) {
                f32x4 sc3 = *(const f32x4*)&s_a[j * 16 + l4 * 4];
                f32x4 sh3 = *(const f32x4*)&s_b[j * 16 + l4 * 4];
                f32x4 o;
#pragma unroll
                for (int r = 0; r < 4; ++r)
                    o[r] = tanh_e(fmaf(acc[j][r] + xv[j][r], sc3[r], sh3[r]));
                __builtin_nontemporal_store(o, (f32x4*)(rp + j * 16));
            }
        } else {
#pragma unroll
            for (int j = 0; j < 8; ++j)
#pragma unroll
                for (int r = 0; r < 4; ++r) {
                    float v = acc[j][r] + xv[j][r];
                    csum[j][r] += v;
                    csq[j][r] = fmaf(v, v, csq[j][r]);
                }
        }
    };

    f32x4 xv0[8], xv1[8];
    LOADX(xv0, 0);
#pragma unroll
    for (int h = 0; h < 4; ++h) {
        LOADX(xv1, 2 * h + 1);
        TILE(xv0, 2 * h);
        if (h < 3) LOADX(xv0, 2 * h + 2);
        TILE(xv1, 2 * h + 1);
    }

    if (!OUT) {
#pragma unroll
        for (int j = 0; j < 8; ++j)
#pragma unroll
            for (int r = 0; r < 4; ++r) {
                float sm = csum[j][r], q = csq[j][r];
                sm += __shfl_xor(sm, 1); q += __shfl_xor(q, 1);
                sm += __shfl_xor(sm, 2); q += __shfl_xor(q, 2);
                sm += __shfl_xor(sm, 4); q += __shfl_xor(q, 4);
                sm += __shfl_xor(sm, 8); q += __shfl_xor(q, 8);
                if (l15 == 0) {
                    atomicAdd(&s_a[j * 16 + l4 * 4 + r], sm);
                    atomicAdd(&s_b[j * 16 + l4 * 4 + r], q);
                }
            }
        __syncthreads();
        if (tid < D_) {
            atomicAdd(&gsum[p * D_ + tid], s_a[tid]);
            atomicAdd(&gsq [p * D_ + tid], s_b[tid]);
        }
    }
}

// --- BN finalize: scale/shift pre-multiplied by 2*log2(e) for tanh_e -------
__global__ void k_finalize(const float* __restrict__ sum,
                           const float* __restrict__ sumsq,
                           const float* __restrict__ gamma,
                           const float* __restrict__ beta,
                           float* __restrict__ sce, float* __restrict__ she)
{
    const float L2E2 = 2.f * 1.44269504088896340736f;
    int f = blockIdx.x * blockDim.x + threadIdx.x;
    if (f < F_) {
        float mean = sum[f] * (1.f / B_);
        float var  = sumsq[f] * (1.f / B_) - mean * mean;
        float rstd = rsqrtf(var + 1e-5f);
        float sc = gamma[f] * rstd;
        sce[f] = L2E2 * sc;
        she[f] = L2E2 * (beta[f] - mean * sc);
    }
}

extern "C" void kernel_launch(void* const* d_in, const int* in_sizes, int n_in,
                              void* d_out, int out_size, void* d_ws, size_t ws_size,
                              hipStream_t stream) {
    const float* x      = (const float*)d_in[0];
    const float* W1     = (const float*)d_in[1];
    // d_in[2] = bias1 (cancels inside BN1)
    const float* W2     = (const float*)d_in[3];
    // d_in[4] = bias2 (cancels inside BN3)
    const float* gamma1 = (const float*)d_in[5];
    const float* beta1  = (const float*)d_in[6];
    const float* gamma3 = (const float*)d_in[7];
    const float* beta3  = (const float*)d_in[8];

    float* out = (float*)d_out;
    float* S  = (float*)d_ws;                  // 128KB stats block
    float* sum1 = S;                           // zeroed
    float* sq1  = S + 4096;                    // zeroed
    float* sum3 = S + 8192;                    // zeroed
    float* sq3  = S + 12288;                   // zeroed
    float* sce1 = S + 16384;
    float* she1 = S + 20480;
    float* sce3 = S + 24576;
    float* she3 = S + 28672;

    hipMemsetAsync(d_ws, 0, 4 * 4096 * sizeof(float), stream);

    k_stats1<<<BLOCKS, 512, 0, stream>>>(x, W1, sum1, sq1);
    k_finalize<<<F_ / 256, 256, 0, stream>>>(sum1, sq1, gamma1, beta1, sce1, she1);
    k_pass<false><<<BLOCKS, 512, 0, stream>>>(x, out, W1, W2, sce1, she1, sce3, she3, sum3, sq3);
    k_finalize<<<F_ / 256, 256, 0, stream>>>(sum3, sq3, gamma3, beta3, sce3, she3);
    k_pass<true><<<BLOCKS, 512, 0, stream>>>(x, out, W1, W2, sce1, she1, sce3, she3, sum3, sq3);
}

// Round 9
// 1013.749 us; speedup vs baseline: 1.4485x; 1.4485x over previous
//
#include <hip/hip_runtime.h>
#include <hip/hip_bf16.h>
#include <cstdint>
#include <cstddef>

#define B_ 16384
#define F_ 4096
#define P_ 32
#define D_ 128
#define BLOCKS 512     // 16 blocks per partition; 2 blocks/CU x 256 CU = full residency
#define ITERS 8        // tiles of 16 rows per wave: 16*8*8 waves*16 strips = 16384 rows

using f32x4 = __attribute__((ext_vector_type(4))) float;
using s16x8 = __attribute__((ext_vector_type(8))) short;

union abuf { s16x8 v; uint32_t u[4]; };

__device__ inline uint32_t pk_bf16(float a, float b) {
    float2 f; f.x = a; f.y = b;
    union { __hip_bfloat162 h; uint32_t u; } cv;
    cv.h = __float22bfloat162_rn(f);
    return cv.u;
}
// tanh(z) = 1 - 2/(e^{2z}+1); caller passes ze = 2*log2(e)*z (folded into BN)
__device__ inline float tanh_e(float ze) {
    float e = __builtin_amdgcn_exp2f(ze);
    return 1.f - 2.f * __builtin_amdgcn_rcpf(e + 1.f);
}

// Stage W[p] (128x128 f32, row-major [k][c]) into LDS as MFMA A-operand
// fragments with k-permutation k(sp,l4,t) = sp*32 + (t>=4)*16 + l4*4 + (t&3).
// Matches a B-operand built from f32x4 loads at cols j*16 + l4*4 (pairs
// j=2sp,2sp+1). Wave read for (j,sp) = contiguous 1KB -> conflict-free b128.
// 512-thread version: 2048 slots, 4 rounds.
__device__ inline void stage_wp(const float* __restrict__ Wp, short* s_w, int tid) {
#pragma unroll
    for (int it = 0; it < 4; ++it) {
        int slot = it * 512 + tid;
        int l15 = slot & 15;
        int l4  = (slot >> 4) & 3;
        int sp  = (slot >> 6) & 3;
        int j   = slot >> 8;
        const float* s0 = Wp + (size_t)(sp * 32 + l4 * 4) * D_ + j * 16 + l15;
        const float* s1 = s0 + (size_t)16 * D_;
        abuf a;
        a.u[0] = pk_bf16(s0[0],            s0[(size_t)D_]);
        a.u[1] = pk_bf16(s0[(size_t)2*D_], s0[(size_t)3*D_]);
        a.u[2] = pk_bf16(s1[0],            s1[(size_t)D_]);
        a.u[3] = pk_bf16(s1[(size_t)2*D_], s1[(size_t)3*D_]);
        *(s16x8*)((char*)s_w + (size_t)slot * 16) = a.v;
    }
}

// ---- K1: stats of y1 = x @ BD(W1); y1 lives only in registers -------------
// Single x buffer; prefetch of the next tile issued AFTER GEMM1 when xb is
// dead (peak live ~= xb16+acc32+stats64 = 112 <= 128 cap -> no spill).
__global__ __launch_bounds__(512, 2) void k_stats1(
    const float* __restrict__ x, const float* __restrict__ W1,
    float* __restrict__ gsum, float* __restrict__ gsq)
{
    __shared__ short s_w[D_ * D_];
    __shared__ float s_sum[D_], s_sq[D_];
    const int tid = threadIdx.x;
    const int p = blockIdx.x >> 4, strip = blockIdx.x & 15;
    stage_wp(W1 + (size_t)p * D_ * D_, s_w, tid);
    if (tid < D_) { s_sum[tid] = 0.f; s_sq[tid] = 0.f; }
    __syncthreads();
    const int wave = tid >> 6, lane = tid & 63;
    const int l15 = lane & 15, l4 = lane >> 4;
    const int ldsb = lane * 16;

    f32x4 csum[8], csq[8];
#pragma unroll
    for (int j = 0; j < 8; ++j) { csum[j] = (f32x4){0,0,0,0}; csq[j] = (f32x4){0,0,0,0}; }

    auto LOADX = [&](f32x4 (&xv)[8], int it) {
        const int g = strip * 64 + it * 8 + wave;
        const float* ap = x + (size_t)(g * 16 + l15) * F_ + p * D_ + l4 * 4;
#pragma unroll
        for (int j = 0; j < 8; ++j)
            xv[j] = *(const f32x4*)(ap + j * 16);
    };

    f32x4 xv[8];
    LOADX(xv, 0);
#pragma unroll
    for (int it = 0; it < ITERS; ++it) {
        abuf xb[4];
#pragma unroll
        for (int s = 0; s < 4; ++s) {
            xb[s].u[0] = pk_bf16(xv[2*s][0],   xv[2*s][1]);
            xb[s].u[1] = pk_bf16(xv[2*s][2],   xv[2*s][3]);
            xb[s].u[2] = pk_bf16(xv[2*s+1][0], xv[2*s+1][1]);
            xb[s].u[3] = pk_bf16(xv[2*s+1][2], xv[2*s+1][3]);
        }
        f32x4 acc[8];
#pragma unroll
        for (int j = 0; j < 8; ++j) acc[j] = (f32x4){0,0,0,0};
#pragma unroll
        for (int s = 0; s < 4; ++s)
#pragma unroll
            for (int j = 0; j < 8; ++j) {
                s16x8 w = *(const s16x8*)((const char*)s_w + (j * 4 + s) * 1024 + ldsb);
                acc[j] = __builtin_amdgcn_mfma_f32_16x16x32_bf16(w, xb[s].v, acc[j], 0, 0, 0);
            }
        if (it + 1 < ITERS) LOADX(xv, it + 1);   // xb dead; regs free for prefetch
#pragma unroll
        for (int j = 0; j < 8; ++j)
#pragma unroll
            for (int r = 0; r < 4; ++r) {
                float v = acc[j][r];
                csum[j][r] += v;
                csq[j][r] = fmaf(v, v, csq[j][r]);
            }
    }
#pragma unroll
    for (int j = 0; j < 8; ++j)
#pragma unroll
        for (int r = 0; r < 4; ++r) {
            float sm = csum[j][r], q = csq[j][r];
            sm += __shfl_xor(sm, 1); q += __shfl_xor(q, 1);
            sm += __shfl_xor(sm, 2); q += __shfl_xor(q, 2);
            sm += __shfl_xor(sm, 4); q += __shfl_xor(q, 4);
            sm += __shfl_xor(sm, 8); q += __shfl_xor(q, 8);
            if (l15 == 0) {
                atomicAdd(&s_sum[j * 16 + l4 * 4 + r], sm);
                atomicAdd(&s_sq [j * 16 + l4 * 4 + r], q);
            }
        }
    __syncthreads();
    if (tid < D_) {
        atomicAdd(&gsum[p * D_ + tid], s_sum[tid]);
        atomicAdd(&gsq [p * D_ + tid], s_sq[tid]);
    }
}

// ---- K2: stats of y3 = (tanh(bn1(x@W1)) @ BD(W2)) + x; NOTHING stored -----
// Single x buffer. Residual needs x after GEMM2, but keeping xv alive costs
// +32 regs -> instead RE-READ the tile from L2/L3 (cache-hot, read ~1us ago;
// exact f32, no HBM traffic). Peak live ~= acc32+xv32+stats64 = 128.
__global__ __launch_bounds__(512, 2) void k_stats3(
    const float* __restrict__ x,
    const float* __restrict__ W1, const float* __restrict__ W2,
    const float* __restrict__ sce1, const float* __restrict__ she1,
    float* __restrict__ gsum, float* __restrict__ gsq)
{
    __shared__ short s_w1[D_ * D_];
    __shared__ short s_w2[D_ * D_];
    __shared__ float s_sc1[D_], s_sh1[D_];
    __shared__ float s_sum[D_], s_sq[D_];
    const int tid = threadIdx.x;
    const int p = blockIdx.x >> 4, strip = blockIdx.x & 15;
    stage_wp(W1 + (size_t)p * D_ * D_, s_w1, tid);
    stage_wp(W2 + (size_t)p * D_ * D_, s_w2, tid);
    if (tid < D_) {
        s_sc1[tid] = sce1[p * D_ + tid];
        s_sh1[tid] = she1[p * D_ + tid];
        s_sum[tid] = 0.f; s_sq[tid] = 0.f;
    }
    __syncthreads();
    const int wave = tid >> 6, lane = tid & 63;
    const int l15 = lane & 15, l4 = lane >> 4;
    const int ldsb = lane * 16;

    f32x4 csum[8], csq[8];
#pragma unroll
    for (int j = 0; j < 8; ++j) { csum[j] = (f32x4){0,0,0,0}; csq[j] = (f32x4){0,0,0,0}; }

    auto LOADX = [&](f32x4 (&xv)[8], int it) {
        const int g = strip * 64 + it * 8 + wave;
        const float* ap = x + (size_t)(g * 16 + l15) * F_ + p * D_ + l4 * 4;
#pragma unroll
        for (int j = 0; j < 8; ++j)
            xv[j] = *(const f32x4*)(ap + j * 16);
    };

    f32x4 xv[8];
    LOADX(xv, 0);
#pragma unroll
    for (int it = 0; it < ITERS; ++it) {
        // GEMM1 fragments (xv dies here)
        abuf xb[4];
#pragma unroll
        for (int s = 0; s < 4; ++s) {
            xb[s].u[0] = pk_bf16(xv[2*s][0],   xv[2*s][1]);
            xb[s].u[1] = pk_bf16(xv[2*s][2],   xv[2*s][3]);
            xb[s].u[2] = pk_bf16(xv[2*s+1][0], xv[2*s+1][1]);
            xb[s].u[3] = pk_bf16(xv[2*s+1][2], xv[2*s+1][3]);
        }
        f32x4 acc[8];
#pragma unroll
        for (int j = 0; j < 8; ++j) acc[j] = (f32x4){0,0,0,0};
#pragma unroll
        for (int s = 0; s < 4; ++s)
#pragma unroll
            for (int j = 0; j < 8; ++j) {
                s16x8 w = *(const s16x8*)((const char*)s_w1 + (j * 4 + s) * 1024 + ldsb);
                acc[j] = __builtin_amdgcn_mfma_f32_16x16x32_bf16(w, xb[s].v, acc[j], 0, 0, 0);
            }
        // bn1 + tanh -> GEMM2 fragments (acc dies progressively)
        abuf tb[4];
#pragma unroll
        for (int sp = 0; sp < 4; ++sp) {
            const int kb = sp * 32 + l4 * 4;
            f32x4 sc0 = *(const f32x4*)&s_sc1[kb], sc1 = *(const f32x4*)&s_sc1[kb + 16];
            f32x4 sh0 = *(const f32x4*)&s_sh1[kb], sh1 = *(const f32x4*)&s_sh1[kb + 16];
            float t0[4], t1[4];
#pragma unroll
            for (int q = 0; q < 4; ++q) {
                t0[q] = tanh_e(fmaf(acc[2*sp][q],   sc0[q], sh0[q]));
                t1[q] = tanh_e(fmaf(acc[2*sp+1][q], sc1[q], sh1[q]));
            }
            tb[sp].u[0] = pk_bf16(t0[0], t0[1]);
            tb[sp].u[1] = pk_bf16(t0[2], t0[3]);
            tb[sp].u[2] = pk_bf16(t1[0], t1[1]);
            tb[sp].u[3] = pk_bf16(t1[2], t1[3]);
        }
        // GEMM2
#pragma unroll
        for (int j = 0; j < 8; ++j) acc[j] = (f32x4){0,0,0,0};
#pragma unroll
        for (int sp = 0; sp < 4; ++sp)
#pragma unroll
            for (int j = 0; j < 8; ++j) {
                s16x8 w = *(const s16x8*)((const char*)s_w2 + (j * 4 + sp) * 1024 + ldsb);
                acc[j] = __builtin_amdgcn_mfma_f32_16x16x32_bf16(w, tb[sp].v, acc[j], 0, 0, 0);
            }
        // residual re-read (L2/L3-hot, exact f32) + stats
        LOADX(xv, it);
#pragma unroll
        for (int j = 0; j < 8; ++j)
#pragma unroll
            for (int r = 0; r < 4; ++r) {
                float v = acc[j][r] + xv[j][r];
                csum[j][r] += v;
                csq[j][r] = fmaf(v, v, csq[j][r]);
            }
        if (it + 1 < ITERS) LOADX(xv, it + 1);
    }
#pragma unroll
    for (int j = 0; j < 8; ++j)
#pragma unroll
        for (int r = 0; r < 4; ++r) {
            float sm = csum[j][r], q = csq[j][r];
            sm += __shfl_xor(sm, 1); q += __shfl_xor(q, 1);
            sm += __shfl_xor(sm, 2); q += __shfl_xor(q, 2);
            sm += __shfl_xor(sm, 4); q += __shfl_xor(q, 4);
            sm += __shfl_xor(sm, 8); q += __shfl_xor(q, 8);
            if (l15 == 0) {
                atomicAdd(&s_sum[j * 16 + l4 * 4 + r], sm);
                atomicAdd(&s_sq [j * 16 + l4 * 4 + r], q);
            }
        }
    __syncthreads();
    if (tid < D_) {
        atomicAdd(&gsum[p * D_ + tid], s_sum[tid]);
        atomicAdd(&gsq [p * D_ + tid], s_sq[tid]);
    }
}

// ---- K3: recompute y3 again, apply bn3+tanh, write o3 (f32) to d_out ------
// No stats registers -> double-buffered x, residual straight from registers.
// Arithmetic identical to k_stats3's y3 (same GEMM order, exact f32 x).
__global__ __launch_bounds__(512, 2) void k_out(
    const float* __restrict__ x, float* __restrict__ out,
    const float* __restrict__ W1, const float* __restrict__ W2,
    const float* __restrict__ sce1, const float* __restrict__ she1,
    const float* __restrict__ sce3, const float* __restrict__ she3)
{
    __shared__ short s_w1[D_ * D_];
    __shared__ short s_w2[D_ * D_];
    __shared__ float s_sc1[D_], s_sh1[D_];
    __shared__ float s_sc3[D_], s_sh3[D_];
    const int tid = threadIdx.x;
    const int p = blockIdx.x >> 4, strip = blockIdx.x & 15;
    stage_wp(W1 + (size_t)p * D_ * D_, s_w1, tid);
    stage_wp(W2 + (size_t)p * D_ * D_, s_w2, tid);
    if (tid < D_) {
        s_sc1[tid] = sce1[p * D_ + tid];
        s_sh1[tid] = she1[p * D_ + tid];
        s_sc3[tid] = sce3[p * D_ + tid];
        s_sh3[tid] = she3[p * D_ + tid];
    }
    __syncthreads();
    const int wave = tid >> 6, lane = tid & 63;
    const int l15 = lane & 15, l4 = lane >> 4;
    const int ldsb = lane * 16;

    auto LOADX = [&](f32x4 (&xv)[8], int it) {
        const int g = strip * 64 + it * 8 + wave;
        const float* ap = x + (size_t)(g * 16 + l15) * F_ + p * D_ + l4 * 4;
#pragma unroll
        for (int j = 0; j < 8; ++j)
            xv[j] = *(const f32x4*)(ap + j * 16);
    };

    auto TILE = [&](f32x4 (&xv)[8], int it) {
        abuf xb[4];
#pragma unroll
        for (int s = 0; s < 4; ++s) {
            xb[s].u[0] = pk_bf16(xv[2*s][0],   xv[2*s][1]);
            xb[s].u[1] = pk_bf16(xv[2*s][2],   xv[2*s][3]);
            xb[s].u[2] = pk_bf16(xv[2*s+1][0], xv[2*s+1][1]);
            xb[s].u[3] = pk_bf16(xv[2*s+1][2], xv[2*s+1][3]);
        }
        f32x4 acc[8];
#pragma unroll
        for (int j = 0; j < 8; ++j) acc[j] = (f32x4){0,0,0,0};
#pragma unroll
        for (int s = 0; s < 4; ++s)
#pragma unroll
            for (int j = 0; j < 8; ++j) {
                s16x8 w = *(const s16x8*)((const char*)s_w1 + (j * 4 + s) * 1024 + ldsb);
                acc[j] = __builtin_amdgcn_mfma_f32_16x16x32_bf16(w, xb[s].v, acc[j], 0, 0, 0);
            }
        abuf tb[4];
#pragma unroll
        for (int sp = 0; sp < 4; ++sp) {
            const int kb = sp * 32 + l4 * 4;
            f32x4 sc0 = *(const f32x4*)&s_sc1[kb], sc1 = *(const f32x4*)&s_sc1[kb + 16];
            f32x4 sh0 = *(const f32x4*)&s_sh1[kb], sh1 = *(const f32x4*)&s_sh1[kb + 16];
            float t0[4], t1[4];
#pragma unroll
            for (int q = 0; q < 4; ++q) {
                t0[q] = tanh_e(fmaf(acc[2*sp][q],   sc0[q], sh0[q]));
                t1[q] = tanh_e(fmaf(acc[2*sp+1][q], sc1[q], sh1[q]));
            }
            tb[sp].u[0] = pk_bf16(t0[0], t0[1]);
            tb[sp].u[1] = pk_bf16(t0[2], t0[3]);
            tb[sp].u[2] = pk_bf16(t1[0], t1[1]);
            tb[sp].u[3] = pk_bf16(t1[2], t1[3]);
        }
#pragma unroll
        for (int j = 0; j < 8; ++j) acc[j] = (f32x4){0,0,0,0};
#pragma unroll
        for (int sp = 0; sp < 4; ++sp)
#pragma unroll
            for (int j = 0; j < 8; ++j) {
                s16x8 w = *(const s16x8*)((const char*)s_w2 + (j * 4 + sp) * 1024 + ldsb);
                acc[j] = __builtin_amdgcn_mfma_f32_16x16x32_bf16(w, tb[sp].v, acc[j], 0, 0, 0);
            }
        const int g = strip * 64 + it * 8 + wave;
        float* rp = out + (size_t)(g * 16 + l15) * F_ + p * D_ + l4 * 4;
#pragma unroll
        for (int j = 0; j < 8; ++j) {
            f32x4 sc3 = *(const f32x4*)&s_sc3[j * 16 + l4 * 4];
            f32x4 sh3 = *(const f32x4*)&s_sh3[j * 16 + l4 * 4];
            f32x4 o;
#pragma unroll
            for (int r = 0; r < 4; ++r)
                o[r] = tanh_e(fmaf(acc[j][r] + xv[j][r], sc3[r], sh3[r]));
            __builtin_nontemporal_store(o, (f32x4*)(rp + j * 16));
        }
    };

    f32x4 xv0[8], xv1[8];
    LOADX(xv0, 0);
#pragma unroll
    for (int h = 0; h < 4; ++h) {
        LOADX(xv1, 2 * h + 1);
        TILE(xv0, 2 * h);
        if (h < 3) LOADX(xv0, 2 * h + 2);
        TILE(xv1, 2 * h + 1);
    }
}

// --- BN finalize: scale/shift pre-multiplied by 2*log2(e) for tanh_e -------
__global__ void k_finalize(const float* __restrict__ sum,
                           const float* __restrict__ sumsq,
                           const float* __restrict__ gamma,
                           const float* __restrict__ beta,
                           float* __restrict__ sce, float* __restrict__ she)
{
    const float L2E2 = 2.f * 1.44269504088896340736f;
    int f = blockIdx.x * blockDim.x + threadIdx.x;
    if (f < F_) {
        float mean = sum[f] * (1.f / B_);
        float var  = sumsq[f] * (1.f / B_) - mean * mean;
        float rstd = rsqrtf(var + 1e-5f);
        float sc = gamma[f] * rstd;
        sce[f] = L2E2 * sc;
        she[f] = L2E2 * (beta[f] - mean * sc);
    }
}

extern "C" void kernel_launch(void* const* d_in, const int* in_sizes, int n_in,
                              void* d_out, int out_size, void* d_ws, size_t ws_size,
                              hipStream_t stream) {
    const float* x      = (const float*)d_in[0];
    const float* W1     = (const float*)d_in[1];
    // d_in[2] = bias1 (cancels inside BN1)
    const float* W2     = (const float*)d_in[3];
    // d_in[4] = bias2 (cancels inside BN3)
    const float* gamma1 = (const float*)d_in[5];
    const float* beta1  = (const float*)d_in[6];
    const float* gamma3 = (const float*)d_in[7];
    const float* beta3  = (const float*)d_in[8];

    float* out = (float*)d_out;
    float* S  = (float*)d_ws;                  // 128KB stats block
    float* sum1 = S;                           // zeroed
    float* sq1  = S + 4096;                    // zeroed
    float* sum3 = S + 8192;                    // zeroed
    float* sq3  = S + 12288;                   // zeroed
    float* sce1 = S + 16384;
    float* she1 = S + 20480;
    float* sce3 = S + 24576;
    float* she3 = S + 28672;

    hipMemsetAsync(d_ws, 0, 4 * 4096 * sizeof(float), stream);

    k_stats1<<<BLOCKS, 512, 0, stream>>>(x, W1, sum1, sq1);
    k_finalize<<<F_ / 256, 256, 0, stream>>>(sum1, sq1, gamma1, beta1, sce1, she1);
    k_stats3<<<BLOCKS, 512, 0, stream>>>(x, W1, W2, sce1, she1, sum3, sq3);
    k_finalize<<<F_ / 256, 256, 0, stream>>>(sum3, sq3, gamma3, beta3, sce3, she3);
    k_out<<<BLOCKS, 512, 0, stream>>>(x, out, W1, W2, sce1, she1, sce3, she3);
}

// Round 10
// 906.049 us; speedup vs baseline: 1.6206x; 1.1189x over previous
//
#include <hip/hip_runtime.h>
#include <hip/hip_bf16.h>
#include <cstdint>
#include <cstddef>

#define B_ 16384
#define F_ 4096
#define P_ 32
#define D_ 128
#define BLOCKS 512     // 16 blocks per partition; VGPR<=128 -> 16 waves/CU
#define ITERS 8        // tiles of 16 rows per wave: 16*8*8 waves*16 strips = 16384

using f32x4 = __attribute__((ext_vector_type(4))) float;
using s16x8 = __attribute__((ext_vector_type(8))) short;

union abuf { s16x8 v; uint32_t u[4]; };

__device__ inline uint32_t pk_bf16(float a, float b) {
    float2 f; f.x = a; f.y = b;
    union { __hip_bfloat162 h; uint32_t u; } cv;
    cv.h = __float22bfloat162_rn(f);
    return cv.u;
}
// tanh(z) = 1 - 2/(e^{2z}+1); caller passes ze = 2*log2(e)*z (folded into BN)
__device__ inline float tanh_e(float ze) {
    float e = __builtin_amdgcn_exp2f(ze);
    return 1.f - 2.f * __builtin_amdgcn_rcpf(e + 1.f);
}

// ---- W staging, NON-swapped B-operand fragment order (K1) -----------------
// slot (j,s,l4,l15) at byte slot*16 holds bf16 W[s*32+l4*8+t][j*16+l15],
// t=0..7. Wave read for (j,s) = contiguous 1KB -> conflict-free b128.
__device__ inline void stage_wb(const float* __restrict__ Wp, short* s_w, int tid) {
#pragma unroll
    for (int it = 0; it < 4; ++it) {
        int slot = it * 512 + tid;
        int l15 = slot & 15;
        int l4  = (slot >> 4) & 3;
        int s   = (slot >> 6) & 3;
        int j   = slot >> 8;
        const float* src = Wp + (size_t)(s * 32 + l4 * 8) * D_ + j * 16 + l15;
        abuf a;
#pragma unroll
        for (int q = 0; q < 4; ++q)
            a.u[q] = pk_bf16(src[(size_t)(2 * q) * D_], src[(size_t)(2 * q + 1) * D_]);
        *(s16x8*)((char*)s_w + (size_t)slot * 16) = a.v;
    }
}

// ---- W staging, swapped A-operand fragment order (K2/K3) ------------------
// k-permutation k(sp,l4,t) = sp*32 + (t>=4)*16 + l4*4 + (t&3): matches a
// B-operand built from f32x4 loads at cols j*16 + l4*4 (pairs j=2sp,2sp+1).
__device__ inline void stage_wp(const float* __restrict__ Wp, short* s_w, int tid) {
#pragma unroll
    for (int it = 0; it < 4; ++it) {
        int slot = it * 512 + tid;
        int l15 = slot & 15;
        int l4  = (slot >> 4) & 3;
        int sp  = (slot >> 6) & 3;
        int j   = slot >> 8;
        const float* s0 = Wp + (size_t)(sp * 32 + l4 * 4) * D_ + j * 16 + l15;
        const float* s1 = s0 + (size_t)16 * D_;
        abuf a;
        a.u[0] = pk_bf16(s0[0],            s0[(size_t)D_]);
        a.u[1] = pk_bf16(s0[(size_t)2*D_], s0[(size_t)3*D_]);
        a.u[2] = pk_bf16(s1[0],            s1[(size_t)D_]);
        a.u[3] = pk_bf16(s1[(size_t)2*D_], s1[(size_t)3*D_]);
        *(s16x8*)((char*)s_w + (size_t)slot * 16) = a.v;
    }
}

// ---- K1: stats of y1 = x @ BD(W1), NON-swapped (A=x, B=W) -----------------
// Lane's D covers 8 columns (j*16+l15) -> stats = 16 persistent regs.
__global__ __launch_bounds__(512, 2) void k_stats1(
    const float* __restrict__ x, const float* __restrict__ W1,
    float* __restrict__ gsum, float* __restrict__ gsq)
{
    __shared__ short s_w[D_ * D_];
    __shared__ float s_sum[D_], s_sq[D_];
    const int tid = threadIdx.x;
    const int p = blockIdx.x >> 4, strip = blockIdx.x & 15;
    stage_wb(W1 + (size_t)p * D_ * D_, s_w, tid);
    if (tid < D_) { s_sum[tid] = 0.f; s_sq[tid] = 0.f; }
    __syncthreads();
    const int wave = tid >> 6, lane = tid & 63;
    const int l15 = lane & 15, l4 = lane >> 4;
    const int ldsb = lane * 16;

    float csum[8], csq[8];
#pragma unroll
    for (int j = 0; j < 8; ++j) { csum[j] = 0.f; csq[j] = 0.f; }

    auto LOADX = [&](f32x4 (&xv)[8], int it) {
        const int g = strip * 64 + it * 8 + wave;
        const float* ap = x + (size_t)(g * 16 + l15) * F_ + p * D_ + l4 * 8;
#pragma unroll
        for (int s = 0; s < 4; ++s) {
            xv[2 * s]     = *(const f32x4*)(ap + s * 32);
            xv[2 * s + 1] = *(const f32x4*)(ap + s * 32 + 4);
        }
    };

    auto TILE = [&](f32x4 (&xv)[8]) {
        abuf a[4];
#pragma unroll
        for (int s = 0; s < 4; ++s) {
            a[s].u[0] = pk_bf16(xv[2*s][0],   xv[2*s][1]);
            a[s].u[1] = pk_bf16(xv[2*s][2],   xv[2*s][3]);
            a[s].u[2] = pk_bf16(xv[2*s+1][0], xv[2*s+1][1]);
            a[s].u[3] = pk_bf16(xv[2*s+1][2], xv[2*s+1][3]);
        }
        f32x4 acc[8];
#pragma unroll
        for (int j = 0; j < 8; ++j) acc[j] = (f32x4){0,0,0,0};
#pragma unroll
        for (int s = 0; s < 4; ++s)
#pragma unroll
            for (int j = 0; j < 8; ++j) {
                s16x8 b = *(const s16x8*)((const char*)s_w + (j * 4 + s) * 1024 + ldsb);
                acc[j] = __builtin_amdgcn_mfma_f32_16x16x32_bf16(a[s].v, b, acc[j], 0, 0, 0);
            }
        // acc[j][r] = y1[row g*16 + l4*4 + r][col p*128 + j*16 + l15]
#pragma unroll
        for (int j = 0; j < 8; ++j)
#pragma unroll
            for (int r = 0; r < 4; ++r) {
                float v = acc[j][r];
                csum[j] += v;
                csq[j] = fmaf(v, v, csq[j]);
            }
    };

    f32x4 xv0[8], xv1[8];
    LOADX(xv0, 0);
#pragma unroll
    for (int h = 0; h < 4; ++h) {
        LOADX(xv1, 2 * h + 1);
        TILE(xv0);
        if (h < 3) LOADX(xv0, 2 * h + 2);
        TILE(xv1);
    }

    // reduce over rows (lane bits 4,5 = l4) -> l4==0 lanes hold col totals
#pragma unroll
    for (int j = 0; j < 8; ++j) {
        float sm = csum[j], q = csq[j];
        sm += __shfl_xor(sm, 16); q += __shfl_xor(q, 16);
        sm += __shfl_xor(sm, 32); q += __shfl_xor(q, 32);
        if (l4 == 0) {
            atomicAdd(&s_sum[j * 16 + l15], sm);
            atomicAdd(&s_sq [j * 16 + l15], q);
        }
    }
    __syncthreads();
    if (tid < D_) {
        atomicAdd(&gsum[p * D_ + tid], s_sum[tid]);
        atomicAdd(&gsq [p * D_ + tid], s_sq[tid]);
    }
}

// ---- K2: stats of y3 = tanh(bn1(x@W1)) @ BD(W2) + x; nothing stored -------
// Swapped orientation; NO persistent stat regs: per-tile butterfly over the
// 16 batch rows (lane bits 0-3) + atomicAdd into LDS from l15==0 lanes.
// Residual x re-read from L2/L3 (same addresses ~1us earlier; exact f32).
__global__ __launch_bounds__(512, 2) void k_stats3(
    const float* __restrict__ x,
    const float* __restrict__ W1, const float* __restrict__ W2,
    const float* __restrict__ sce1, const float* __restrict__ she1,
    float* __restrict__ gsum, float* __restrict__ gsq)
{
    __shared__ short s_w1[D_ * D_];
    __shared__ short s_w2[D_ * D_];
    __shared__ float s_sc1[D_], s_sh1[D_];
    __shared__ float s_sum[D_], s_sq[D_];
    const int tid = threadIdx.x;
    const int p = blockIdx.x >> 4, strip = blockIdx.x & 15;
    stage_wp(W1 + (size_t)p * D_ * D_, s_w1, tid);
    stage_wp(W2 + (size_t)p * D_ * D_, s_w2, tid);
    if (tid < D_) {
        s_sc1[tid] = sce1[p * D_ + tid];
        s_sh1[tid] = she1[p * D_ + tid];
        s_sum[tid] = 0.f; s_sq[tid] = 0.f;
    }
    __syncthreads();
    const int wave = tid >> 6, lane = tid & 63;
    const int l15 = lane & 15, l4 = lane >> 4;
    const int ldsb = lane * 16;

    auto LOADX = [&](f32x4 (&xv)[8], int it) {
        const int g = strip * 64 + it * 8 + wave;
        const float* ap = x + (size_t)(g * 16 + l15) * F_ + p * D_ + l4 * 4;
#pragma unroll
        for (int j = 0; j < 8; ++j)
            xv[j] = *(const f32x4*)(ap + j * 16);
    };

    auto TILE = [&](f32x4 (&xv)[8], int it) {
        abuf xb[4];
#pragma unroll
        for (int s = 0; s < 4; ++s) {
            xb[s].u[0] = pk_bf16(xv[2*s][0],   xv[2*s][1]);
            xb[s].u[1] = pk_bf16(xv[2*s][2],   xv[2*s][3]);
            xb[s].u[2] = pk_bf16(xv[2*s+1][0], xv[2*s+1][1]);
            xb[s].u[3] = pk_bf16(xv[2*s+1][2], xv[2*s+1][3]);
        }
        f32x4 acc[8];
#pragma unroll
        for (int j = 0; j < 8; ++j) acc[j] = (f32x4){0,0,0,0};
#pragma unroll
        for (int s = 0; s < 4; ++s)
#pragma unroll
            for (int j = 0; j < 8; ++j) {
                s16x8 w = *(const s16x8*)((const char*)s_w1 + (j * 4 + s) * 1024 + ldsb);
                acc[j] = __builtin_amdgcn_mfma_f32_16x16x32_bf16(w, xb[s].v, acc[j], 0, 0, 0);
            }
        abuf tb[4];
#pragma unroll
        for (int sp = 0; sp < 4; ++sp) {
            const int kb = sp * 32 + l4 * 4;
            f32x4 sc0 = *(const f32x4*)&s_sc1[kb], sc1 = *(const f32x4*)&s_sc1[kb + 16];
            f32x4 sh0 = *(const f32x4*)&s_sh1[kb], sh1 = *(const f32x4*)&s_sh1[kb + 16];
            float t0[4], t1[4];
#pragma unroll
            for (int q = 0; q < 4; ++q) {
                t0[q] = tanh_e(fmaf(acc[2*sp][q],   sc0[q], sh0[q]));
                t1[q] = tanh_e(fmaf(acc[2*sp+1][q], sc1[q], sh1[q]));
            }
            tb[sp].u[0] = pk_bf16(t0[0], t0[1]);
            tb[sp].u[1] = pk_bf16(t0[2], t0[3]);
            tb[sp].u[2] = pk_bf16(t1[0], t1[1]);
            tb[sp].u[3] = pk_bf16(t1[2], t1[3]);
        }
#pragma unroll
        for (int j = 0; j < 8; ++j) acc[j] = (f32x4){0,0,0,0};
#pragma unroll
        for (int sp = 0; sp < 4; ++sp)
#pragma unroll
            for (int j = 0; j < 8; ++j) {
                s16x8 w = *(const s16x8*)((const char*)s_w2 + (j * 4 + sp) * 1024 + ldsb);
                acc[j] = __builtin_amdgcn_mfma_f32_16x16x32_bf16(w, tb[sp].v, acc[j], 0, 0, 0);
            }
        // residual re-read (cache-hot) + per-tile stats flush
        const int g = strip * 64 + it * 8 + wave;
        const float* xp = x + (size_t)(g * 16 + l15) * F_ + p * D_ + l4 * 4;
        f32x4 xr[8];
#pragma unroll
        for (int j = 0; j < 8; ++j) xr[j] = *(const f32x4*)(xp + j * 16);
#pragma unroll
        for (int j = 0; j < 8; ++j)
#pragma unroll
            for (int r = 0; r < 4; ++r) {
                float v = acc[j][r] + xr[j][r];
                float q = v * v;
                v += __shfl_xor(v, 1); q += __shfl_xor(q, 1);
                v += __shfl_xor(v, 2); q += __shfl_xor(q, 2);
                v += __shfl_xor(v, 4); q += __shfl_xor(q, 4);
                v += __shfl_xor(v, 8); q += __shfl_xor(q, 8);
                if (l15 == 0) {
                    atomicAdd(&s_sum[j * 16 + l4 * 4 + r], v);
                    atomicAdd(&s_sq [j * 16 + l4 * 4 + r], q);
                }
            }
    };

    f32x4 xv0[8], xv1[8];
    LOADX(xv0, 0);
#pragma unroll
    for (int h = 0; h < 4; ++h) {
        LOADX(xv1, 2 * h + 1);
        TILE(xv0, 2 * h);
        if (h < 3) LOADX(xv0, 2 * h + 2);
        TILE(xv1, 2 * h + 1);
    }

    __syncthreads();
    if (tid < D_) {
        atomicAdd(&gsum[p * D_ + tid], s_sum[tid]);
        atomicAdd(&gsq [p * D_ + tid], s_sq[tid]);
    }
}

// ---- K3: recompute y3, apply bn3+tanh, write o3 (f32) to d_out ------------
// Identical y3 arithmetic to k_stats3 (same fragments, same re-read residual).
__global__ __launch_bounds__(512, 2) void k_out(
    const float* __restrict__ x, float* __restrict__ out,
    const float* __restrict__ W1, const float* __restrict__ W2,
    const float* __restrict__ sce1, const float* __restrict__ she1,
    const float* __restrict__ sce3, const float* __restrict__ she3)
{
    __shared__ short s_w1[D_ * D_];
    __shared__ short s_w2[D_ * D_];
    __shared__ float s_sc1[D_], s_sh1[D_];
    __shared__ float s_sc3[D_], s_sh3[D_];
    const int tid = threadIdx.x;
    const int p = blockIdx.x >> 4, strip = blockIdx.x & 15;
    stage_wp(W1 + (size_t)p * D_ * D_, s_w1, tid);
    stage_wp(W2 + (size_t)p * D_ * D_, s_w2, tid);
    if (tid < D_) {
        s_sc1[tid] = sce1[p * D_ + tid];
        s_sh1[tid] = she1[p * D_ + tid];
        s_sc3[tid] = sce3[p * D_ + tid];
        s_sh3[tid] = she3[p * D_ + tid];
    }
    __syncthreads();
    const int wave = tid >> 6, lane = tid & 63;
    const int l15 = lane & 15, l4 = lane >> 4;
    const int ldsb = lane * 16;

    auto LOADX = [&](f32x4 (&xv)[8], int it) {
        const int g = strip * 64 + it * 8 + wave;
        const float* ap = x + (size_t)(g * 16 + l15) * F_ + p * D_ + l4 * 4;
#pragma unroll
        for (int j = 0; j < 8; ++j)
            xv[j] = *(const f32x4*)(ap + j * 16);
    };

    auto TILE = [&](f32x4 (&xv)[8], int it) {
        abuf xb[4];
#pragma unroll
        for (int s = 0; s < 4; ++s) {
            xb[s].u[0] = pk_bf16(xv[2*s][0],   xv[2*s][1]);
            xb[s].u[1] = pk_bf16(xv[2*s][2],   xv[2*s][3]);
            xb[s].u[2] = pk_bf16(xv[2*s+1][0], xv[2*s+1][1]);
            xb[s].u[3] = pk_bf16(xv[2*s+1][2], xv[2*s+1][3]);
        }
        f32x4 acc[8];
#pragma unroll
        for (int j = 0; j < 8; ++j) acc[j] = (f32x4){0,0,0,0};
#pragma unroll
        for (int s = 0; s < 4; ++s)
#pragma unroll
            for (int j = 0; j < 8; ++j) {
                s16x8 w = *(const s16x8*)((const char*)s_w1 + (j * 4 + s) * 1024 + ldsb);
                acc[j] = __builtin_amdgcn_mfma_f32_16x16x32_bf16(w, xb[s].v, acc[j], 0, 0, 0);
            }
        abuf tb[4];
#pragma unroll
        for (int sp = 0; sp < 4; ++sp) {
            const int kb = sp * 32 + l4 * 4;
            f32x4 sc0 = *(const f32x4*)&s_sc1[kb], sc1 = *(const f32x4*)&s_sc1[kb + 16];
            f32x4 sh0 = *(const f32x4*)&s_sh1[kb], sh1 = *(const f32x4*)&s_sh1[kb + 16];
            float t0[4], t1[4];
#pragma unroll
            for (int q = 0; q < 4; ++q) {
                t0[q] = tanh_e(fmaf(acc[2*sp][q],   sc0[q], sh0[q]));
                t1[q] = tanh_e(fmaf(acc[2*sp+1][q], sc1[q], sh1[q]));
            }
            tb[sp].u[0] = pk_bf16(t0[0], t0[1]);
            tb[sp].u[1] = pk_bf16(t0[2], t0[3]);
            tb[sp].u[2] = pk_bf16(t1[0], t1[1]);
            tb[sp].u[3] = pk_bf16(t1[2], t1[3]);
        }
#pragma unroll
        for (int j = 0; j < 8; ++j) acc[j] = (f32x4){0,0,0,0};
#pragma unroll
        for (int sp = 0; sp < 4; ++sp)
#pragma unroll
            for (int j = 0; j < 8; ++j) {
                s16x8 w = *(const s16x8*)((const char*)s_w2 + (j * 4 + sp) * 1024 + ldsb);
                acc[j] = __builtin_amdgcn_mfma_f32_16x16x32_bf16(w, tb[sp].v, acc[j], 0, 0, 0);
            }
        const int g = strip * 64 + it * 8 + wave;
        const size_t off = (size_t)(g * 16 + l15) * F_ + p * D_ + l4 * 4;
        const float* xp = x + off;
        f32x4 xr[8];
#pragma unroll
        for (int j = 0; j < 8; ++j) xr[j] = *(const f32x4*)(xp + j * 16);
        float* rp = out + off;
#pragma unroll
        for (int j = 0; j < 8; ++j) {
            f32x4 sc3 = *(const f32x4*)&s_sc3[j * 16 + l4 * 4];
            f32x4 sh3 = *(const f32x4*)&s_sh3[j * 16 + l4 * 4];
            f32x4 o;
#pragma unroll
            for (int r = 0; r < 4; ++r) {
                float v = acc[j][r] + xr[j][r];
                o[r] = tanh_e(fmaf(v, sc3[r], sh3[r]));
            }
            __builtin_nontemporal_store(o, (f32x4*)(rp + j * 16));
        }
    };

    f32x4 xv0[8], xv1[8];
    LOADX(xv0, 0);
#pragma unroll
    for (int h = 0; h < 4; ++h) {
        LOADX(xv1, 2 * h + 1);
        TILE(xv0, 2 * h);
        if (h < 3) LOADX(xv0, 2 * h + 2);
        TILE(xv1, 2 * h + 1);
    }
}

// --- BN finalize: scale/shift pre-multiplied by 2*log2(e) for tanh_e -------
__global__ void k_finalize(const float* __restrict__ sum,
                           const float* __restrict__ sumsq,
                           const float* __restrict__ gamma,
                           const float* __restrict__ beta,
                           float* __restrict__ sce, float* __restrict__ she)
{
    const float L2E2 = 2.f * 1.44269504088896340736f;
    int f = blockIdx.x * blockDim.x + threadIdx.x;
    if (f < F_) {
        float mean = sum[f] * (1.f / B_);
        float var  = sumsq[f] * (1.f / B_) - mean * mean;
        float rstd = rsqrtf(var + 1e-5f);
        float sc = gamma[f] * rstd;
        sce[f] = L2E2 * sc;
        she[f] = L2E2 * (beta[f] - mean * sc);
    }
}

extern "C" void kernel_launch(void* const* d_in, const int* in_sizes, int n_in,
                              void* d_out, int out_size, void* d_ws, size_t ws_size,
                              hipStream_t stream) {
    const float* x      = (const float*)d_in[0];
    const float* W1     = (const float*)d_in[1];
    // d_in[2] = bias1 (cancels inside BN1)
    const float* W2     = (const float*)d_in[3];
    // d_in[4] = bias2 (cancels inside BN3)
    const float* gamma1 = (const float*)d_in[5];
    const float* beta1  = (const float*)d_in[6];
    const float* gamma3 = (const float*)d_in[7];
    const float* beta3  = (const float*)d_in[8];

    float* out = (float*)d_out;
    float* S  = (float*)d_ws;                  // 128KB stats block
    float* sum1 = S;                           // zeroed
    float* sq1  = S + 4096;                    // zeroed
    float* sum3 = S + 8192;                    // zeroed
    float* sq3  = S + 12288;                   // zeroed
    float* sce1 = S + 16384;
    float* she1 = S + 20480;
    float* sce3 = S + 24576;
    float* she3 = S + 28672;

    hipMemsetAsync(d_ws, 0, 4 * 4096 * sizeof(float), stream);

    k_stats1<<<BLOCKS, 512, 0, stream>>>(x, W1, sum1, sq1);
    k_finalize<<<F_ / 256, 256, 0, stream>>>(sum1, sq1, gamma1, beta1, sce1, she1);
    k_stats3<<<BLOCKS, 512, 0, stream>>>(x, W1, W2, sce1, she1, sum3, sq3);
    k_finalize<<<F_ / 256, 256, 0, stream>>>(sum3, sq3, gamma3, beta3, sce3, she3);
    k_out<<<BLOCKS, 512, 0, stream>>>(x, out, W1, W2, sce1, she1, sce3, she3);
}

// Round 11
// 889.914 us; speedup vs baseline: 1.6500x; 1.0181x over previous
//
#include <hip/hip_runtime.h>
#include <hip/hip_bf16.h>
#include <cstdint>
#include <cstddef>

#define B_ 16384
#define F_ 4096
#define P_ 32
#define D_ 128
#define STRIPS 32      // blocks per partition; grid = P_*STRIPS = 1024 (exactly resident)
#define ITERS 4        // per block: 4 iters x 128 rows (8 waves x 16) = 512 rows

using f32x4 = __attribute__((ext_vector_type(4))) float;
using s16x8 = __attribute__((ext_vector_type(8))) short;

union abuf { s16x8 v; uint32_t u[4]; };

__device__ inline uint32_t pk_bf16(float a, float b) {
    float2 f; f.x = a; f.y = b;
    union { __hip_bfloat162 h; uint32_t u; } cv;
    cv.h = __float22bfloat162_rn(f);
    return cv.u;
}
// tanh(z) = 1 - 2/(e^{2z}+1); caller passes ze = 2*log2(e)*z (folded into BN)
__device__ inline float tanh_e(float ze) {
    float e = __builtin_amdgcn_exp2f(ze);
    return 1.f - 2.f * __builtin_amdgcn_rcpf(e + 1.f);
}

// Stage W[p] (128x128 f32, row-major [k][c]) into LDS in MFMA B-fragment
// order: the 16B at slot = (j*4+s)*64 + lane holds bf16 W[s*32+(lane>>4)*8+t]
// [j*16+(lane&15)], t=0..7. A wave's read for (j,s) is a contiguous 1KB
// block (lane*16) -> conflict-free ds_read_b128 (verified: 0 conflicts).
// 512-thread version: 2048 slots, 4 rounds.
__device__ inline void stage_w(const float* __restrict__ Wp, short* s_w, int tid) {
#pragma unroll
    for (int it = 0; it < 4; ++it) {
        int slot = it * 512 + tid;
        int l15 = slot & 15;
        int l4  = (slot >> 4) & 3;
        int s   = (slot >> 6) & 3;
        int j   = slot >> 8;
        const float* src = Wp + (size_t)(s * 32 + l4 * 8) * D_ + j * 16 + l15;
        abuf a;
#pragma unroll
        for (int q = 0; q < 4; ++q)
            a.u[q] = pk_bf16(src[(size_t)(2 * q) * D_], src[(size_t)(2 * q + 1) * D_]);
        *(s16x8*)((char*)s_w + (size_t)slot * 16) = a.v;
    }
}

// ------------- K1: y1 = x @ BD(W1) -> d_out (f32), fused stats1 ------------
// Round-4 proven body (VGPR=64): per wave 16 rows x 128 cols, acc[8].
__global__ __launch_bounds__(512, 8) void k_gemm1(
    const float* __restrict__ x, const float* __restrict__ W1,
    float* __restrict__ y1, float* __restrict__ gsum, float* __restrict__ gsq)
{
    __shared__ short s_w[D_ * D_];
    __shared__ float s_sum[D_], s_sq[D_];
    const int tid = threadIdx.x;
    const int p = blockIdx.x / STRIPS, strip = blockIdx.x % STRIPS;
    stage_w(W1 + (size_t)p * D_ * D_, s_w, tid);
    if (tid < D_) { s_sum[tid] = 0.f; s_sq[tid] = 0.f; }
    __syncthreads();
    const int wave = tid >> 6, lane = tid & 63;
    const int l15 = lane & 15, l4 = lane >> 4;
    const int ldsb = lane * 16;

    float csum[8], csq[8];
#pragma unroll
    for (int j = 0; j < 8; ++j) { csum[j] = 0.f; csq[j] = 0.f; }

    for (int it = 0; it < ITERS; ++it) {
        const int row0 = strip * 512 + it * 128 + wave * 16;
        const float* ap = x + (size_t)(row0 + l15) * F_ + p * D_ + l4 * 8;
        abuf a[4];
#pragma unroll
        for (int s = 0; s < 4; ++s) {
            f32x4 v0 = *(const f32x4*)(ap + s * 32);
            f32x4 v1 = *(const f32x4*)(ap + s * 32 + 4);
            a[s].u[0] = pk_bf16(v0[0], v0[1]);
            a[s].u[1] = pk_bf16(v0[2], v0[3]);
            a[s].u[2] = pk_bf16(v1[0], v1[1]);
            a[s].u[3] = pk_bf16(v1[2], v1[3]);
        }
        f32x4 acc[8];
#pragma unroll
        for (int j = 0; j < 8; ++j) acc[j] = (f32x4){0.f, 0.f, 0.f, 0.f};
#pragma unroll
        for (int s = 0; s < 4; ++s)
#pragma unroll
            for (int j = 0; j < 8; ++j) {
                s16x8 b = *(const s16x8*)((const char*)s_w + (j * 4 + s) * 1024 + ldsb);
                acc[j] = __builtin_amdgcn_mfma_f32_16x16x32_bf16(a[s].v, b, acc[j], 0, 0, 0);
            }
        // D layout: row = row0 + l4*4 + r, col = p*128 + j*16 + l15 (verified)
        const int rb = row0 + l4 * 4;
#pragma unroll
        for (int j = 0; j < 8; ++j) {
            float* yp = y1 + (size_t)rb * F_ + p * D_ + j * 16 + l15;
#pragma unroll
            for (int r = 0; r < 4; ++r) {
                float v = acc[j][r];
                yp[(size_t)r * F_] = v;
                csum[j] += v;
                csq[j] = fmaf(v, v, csq[j]);
            }
        }
    }
#pragma unroll
    for (int j = 0; j < 8; ++j) {
        float sm = csum[j], q = csq[j];
        sm += __shfl_xor(sm, 16); q += __shfl_xor(q, 16);
        sm += __shfl_xor(sm, 32); q += __shfl_xor(q, 32);
        if (l4 == 0) {
            atomicAdd(&s_sum[j * 16 + l15], sm);
            atomicAdd(&s_sq [j * 16 + l15], q);
        }
    }
    __syncthreads();
    if (tid < D_) {
        atomicAdd(&gsum[p * D_ + tid], s_sum[tid]);
        atomicAdd(&gsq [p * D_ + tid], s_sq[tid]);
    }
}

// -- K2: y3 = tanh(bn1(y1)) @ BD(W2) + x, in place over y1, fused stats3 ----
// Round-4 proven body (VGPR=64). Wave-private 16-row tiles: all reads of a
// tile are consumed before its in-place stores (program order) -> safe.
__global__ __launch_bounds__(512, 8) void k_gemm2(
    const float* __restrict__ x, float* __restrict__ yb /* y1 in, y3 out */,
    const float* __restrict__ W2,
    const float* __restrict__ sce, const float* __restrict__ she,
    float* __restrict__ gsum, float* __restrict__ gsq)
{
    __shared__ short s_w[D_ * D_];
    __shared__ float s_sc[D_], s_sh[D_];
    __shared__ float s_sum[D_], s_sq[D_];
    const int tid = threadIdx.x;
    const int p = blockIdx.x / STRIPS, strip = blockIdx.x % STRIPS;
    stage_w(W2 + (size_t)p * D_ * D_, s_w, tid);
    if (tid < D_) {
        s_sc[tid] = sce[p * D_ + tid];
        s_sh[tid] = she[p * D_ + tid];
        s_sum[tid] = 0.f; s_sq[tid] = 0.f;
    }
    __syncthreads();
    const int wave = tid >> 6, lane = tid & 63;
    const int l15 = lane & 15, l4 = lane >> 4;
    const int ldsb = lane * 16;

    float csum[8], csq[8];
#pragma unroll
    for (int j = 0; j < 8; ++j) { csum[j] = 0.f; csq[j] = 0.f; }

    for (int it = 0; it < ITERS; ++it) {
        const int row0 = strip * 512 + it * 128 + wave * 16;
        const float* ap = yb + (size_t)(row0 + l15) * F_ + p * D_ + l4 * 8;
        abuf a[4];
#pragma unroll
        for (int s = 0; s < 4; ++s) {
            const int kb = s * 32 + l4 * 8;
            f32x4 v0 = *(const f32x4*)(ap + s * 32);
            f32x4 v1 = *(const f32x4*)(ap + s * 32 + 4);
            f32x4 sc0 = *(const f32x4*)&s_sc[kb], sc1 = *(const f32x4*)&s_sc[kb + 4];
            f32x4 sh0 = *(const f32x4*)&s_sh[kb], sh1 = *(const f32x4*)&s_sh[kb + 4];
            float t0[4], t1[4];
#pragma unroll
            for (int q = 0; q < 4; ++q) {
                t0[q] = tanh_e(fmaf(v0[q], sc0[q], sh0[q]));
                t1[q] = tanh_e(fmaf(v1[q], sc1[q], sh1[q]));
            }
            a[s].u[0] = pk_bf16(t0[0], t0[1]);
            a[s].u[1] = pk_bf16(t0[2], t0[3]);
            a[s].u[2] = pk_bf16(t1[0], t1[1]);
            a[s].u[3] = pk_bf16(t1[2], t1[3]);
        }
        f32x4 acc[8];
#pragma unroll
        for (int j = 0; j < 8; ++j) acc[j] = (f32x4){0.f, 0.f, 0.f, 0.f};
#pragma unroll
        for (int s = 0; s < 4; ++s)
#pragma unroll
            for (int j = 0; j < 8; ++j) {
                s16x8 b = *(const s16x8*)((const char*)s_w + (j * 4 + s) * 1024 + ldsb);
                acc[j] = __builtin_amdgcn_mfma_f32_16x16x32_bf16(a[s].v, b, acc[j], 0, 0, 0);
            }
        // epilogue: + residual x, store y3 over y1, accumulate stats
        const int rb = row0 + l4 * 4;
#pragma unroll
        for (int j = 0; j < 8; ++j) {
            const size_t off = (size_t)rb * F_ + p * D_ + j * 16 + l15;
            const float* xp = x + off;
            float* yp = yb + off;
#pragma unroll
            for (int r = 0; r < 4; ++r) {
                float v = acc[j][r] + xp[(size_t)r * F_];
                yp[(size_t)r * F_] = v;
                csum[j] += v;
                csq[j] = fmaf(v, v, csq[j]);
            }
        }
    }
#pragma unroll
    for (int j = 0; j < 8; ++j) {
        float sm = csum[j], q = csq[j];
        sm += __shfl_xor(sm, 16); q += __shfl_xor(q, 16);
        sm += __shfl_xor(sm, 32); q += __shfl_xor(q, 32);
        if (l4 == 0) {
            atomicAdd(&s_sum[j * 16 + l15], sm);
            atomicAdd(&s_sq [j * 16 + l15], q);
        }
    }
    __syncthreads();
    if (tid < D_) {
        atomicAdd(&gsum[p * D_ + tid], s_sum[tid]);
        atomicAdd(&gsq [p * D_ + tid], s_sq[tid]);
    }
}

// --- BN finalize: scale/shift pre-multiplied by 2*log2(e) for tanh_e -------
__global__ void k_finalize(const float* __restrict__ sum,
                           const float* __restrict__ sumsq,
                           const float* __restrict__ gamma,
                           const float* __restrict__ beta,
                           float* __restrict__ sce, float* __restrict__ she)
{
    const float L2E2 = 2.f * 1.44269504088896340736f;
    int f = blockIdx.x * blockDim.x + threadIdx.x;
    if (f < F_) {
        float mean = sum[f] * (1.f / B_);
        float var  = sumsq[f] * (1.f / B_) - mean * mean;
        float rstd = rsqrtf(var + 1e-5f);
        float sc = gamma[f] * rstd;
        sce[f] = L2E2 * sc;
        she[f] = L2E2 * (beta[f] - mean * sc);
    }
}

// ----------- K3: o3 = tanh(bn3(y3)), in place on d_out ---------------------
__global__ void k_bn_tanh(float* yb, const float* __restrict__ sce,
                          const float* __restrict__ she)
{
    const size_t n4 = (size_t)B_ * F_ / 4;
    size_t i = (size_t)blockIdx.x * blockDim.x + threadIdx.x;
    const size_t stride = (size_t)gridDim.x * blockDim.x;
    for (; i < n4; i += stride) {
        f32x4 v = ((const f32x4*)yb)[i];
        int col = (int)((i * 4) & (F_ - 1));
        f32x4 sc = *(const f32x4*)(sce + col);
        f32x4 sh = *(const f32x4*)(she + col);
        f32x4 r;
#pragma unroll
        for (int t = 0; t < 4; ++t) r[t] = tanh_e(fmaf(v[t], sc[t], sh[t]));
        __builtin_nontemporal_store(r, (f32x4*)yb + i);
    }
}

extern "C" void kernel_launch(void* const* d_in, const int* in_sizes, int n_in,
                              void* d_out, int out_size, void* d_ws, size_t ws_size,
                              hipStream_t stream) {
    const float* x      = (const float*)d_in[0];
    const float* W1     = (const float*)d_in[1];
    // d_in[2] = bias1 (cancels inside BN1)
    const float* W2     = (const float*)d_in[3];
    // d_in[4] = bias2 (cancels inside BN3)
    const float* gamma1 = (const float*)d_in[5];
    const float* beta1  = (const float*)d_in[6];
    const float* gamma3 = (const float*)d_in[7];
    const float* beta3  = (const float*)d_in[8];

    float* yb = (float*)d_out;          // y1 -> y3 -> o3, all in d_out
    float* S  = (float*)d_ws;           // 128KB stats block
    float* sum1 = S;                    // zeroed
    float* sq1  = S + 4096;             // zeroed
    float* sum3 = S + 8192;             // zeroed
    float* sq3  = S + 12288;            // zeroed
    float* sce1 = S + 16384;
    float* she1 = S + 20480;
    float* sce3 = S + 24576;
    float* she3 = S + 28672;

    hipMemsetAsync(d_ws, 0, 4 * 4096 * sizeof(float), stream);

    k_gemm1<<<P_ * STRIPS, 512, 0, stream>>>(x, W1, yb, sum1, sq1);
    k_finalize<<<F_ / 256, 256, 0, stream>>>(sum1, sq1, gamma1, beta1, sce1, she1);
    k_gemm2<<<P_ * STRIPS, 512, 0, stream>>>(x, yb, W2, sce1, she1, sum3, sq3);
    k_finalize<<<F_ / 256, 256, 0, stream>>>(sum3, sq3, gamma3, beta3, sce3, she3);
    k_bn_tanh<<<8192, 256, 0, stream>>>(yb, sce3, she3);
}

// Round 12
// 690.833 us; speedup vs baseline: 2.1255x; 1.2882x over previous
//
#include <hip/hip_runtime.h>
#include <hip/hip_bf16.h>
#include <cstdint>
#include <cstddef>

#define B_ 16384
#define F_ 4096
#define P_ 32
#define D_ 128
#define STRIPS 32      // blocks per partition; grid = P_*STRIPS = 1024
#define ITERS 4        // per block: 4 iters x 128 rows (8 waves x 16) = 512 rows

using f32x4 = __attribute__((ext_vector_type(4))) float;
using s16x8 = __attribute__((ext_vector_type(8))) short;

union abuf { s16x8 v; uint32_t u[4]; };

__device__ inline uint32_t pk_bf16(float a, float b) {
    float2 f; f.x = a; f.y = b;
    union { __hip_bfloat162 h; uint32_t u; } cv;
    cv.h = __float22bfloat162_rn(f);
    return cv.u;
}
// tanh(z) = 1 - 2/(e^{2z}+1); caller passes ze = 2*log2(e)*z (folded into BN)
__device__ inline float tanh_e(float ze) {
    float e = __builtin_amdgcn_exp2f(ze);
    return 1.f - 2.f * __builtin_amdgcn_rcpf(e + 1.f);
}

// Stage W[p] (128x128 f32, row-major [k][c]) into LDS in MFMA B-fragment
// order: the 16B at slot = (j*4+s)*64 + lane holds bf16 W[s*32+(lane>>4)*8+t]
// [j*16+(lane&15)], t=0..7. A wave's read for (j,s) is a contiguous 1KB
// block (lane*16) -> conflict-free ds_read_b128 (verified: 0 conflicts).
// 512-thread version: 2048 slots, 4 rounds.
__device__ inline void stage_w(const float* __restrict__ Wp, short* s_w, int tid) {
#pragma unroll
    for (int it = 0; it < 4; ++it) {
        int slot = it * 512 + tid;
        int l15 = slot & 15;
        int l4  = (slot >> 4) & 3;
        int s   = (slot >> 6) & 3;
        int j   = slot >> 8;
        const float* src = Wp + (size_t)(s * 32 + l4 * 8) * D_ + j * 16 + l15;
        abuf a;
#pragma unroll
        for (int q = 0; q < 4; ++q)
            a.u[q] = pk_bf16(src[(size_t)(2 * q) * D_], src[(size_t)(2 * q + 1) * D_]);
        *(s16x8*)((char*)s_w + (size_t)slot * 16) = a.v;
    }
}

// ------------- K1: y1 = x @ BD(W1) -> d_out (f32), fused stats1 ------------
// Proven 64-VGPR body; launch_bounds (512,4) => allocator cap 64 (=256/4),
// LDS 34KB => 4 blocks/CU x 8 waves = 32 waves/CU residency.
__global__ __launch_bounds__(512, 4) void k_gemm1(
    const float* __restrict__ x, const float* __restrict__ W1,
    float* __restrict__ y1, float* __restrict__ gsum, float* __restrict__ gsq)
{
    __shared__ short s_w[D_ * D_];
    __shared__ float s_sum[D_], s_sq[D_];
    const int tid = threadIdx.x;
    const int p = blockIdx.x / STRIPS, strip = blockIdx.x % STRIPS;
    stage_w(W1 + (size_t)p * D_ * D_, s_w, tid);
    if (tid < D_) { s_sum[tid] = 0.f; s_sq[tid] = 0.f; }
    __syncthreads();
    const int wave = tid >> 6, lane = tid & 63;
    const int l15 = lane & 15, l4 = lane >> 4;
    const int ldsb = lane * 16;

    float csum[8], csq[8];
#pragma unroll
    for (int j = 0; j < 8; ++j) { csum[j] = 0.f; csq[j] = 0.f; }

    for (int it = 0; it < ITERS; ++it) {
        const int row0 = strip * 512 + it * 128 + wave * 16;
        const float* ap = x + (size_t)(row0 + l15) * F_ + p * D_ + l4 * 8;
        abuf a[4];
#pragma unroll
        for (int s = 0; s < 4; ++s) {
            f32x4 v0 = *(const f32x4*)(ap + s * 32);
            f32x4 v1 = *(const f32x4*)(ap + s * 32 + 4);
            a[s].u[0] = pk_bf16(v0[0], v0[1]);
            a[s].u[1] = pk_bf16(v0[2], v0[3]);
            a[s].u[2] = pk_bf16(v1[0], v1[1]);
            a[s].u[3] = pk_bf16(v1[2], v1[3]);
        }
        f32x4 acc[8];
#pragma unroll
        for (int j = 0; j < 8; ++j) acc[j] = (f32x4){0.f, 0.f, 0.f, 0.f};
#pragma unroll
        for (int s = 0; s < 4; ++s)
#pragma unroll
            for (int j = 0; j < 8; ++j) {
                s16x8 b = *(const s16x8*)((const char*)s_w + (j * 4 + s) * 1024 + ldsb);
                acc[j] = __builtin_amdgcn_mfma_f32_16x16x32_bf16(a[s].v, b, acc[j], 0, 0, 0);
            }
        // D layout: row = row0 + l4*4 + r, col = p*128 + j*16 + l15 (verified)
        const int rb = row0 + l4 * 4;
#pragma unroll
        for (int j = 0; j < 8; ++j) {
            float* yp = y1 + (size_t)rb * F_ + p * D_ + j * 16 + l15;
#pragma unroll
            for (int r = 0; r < 4; ++r) {
                float v = acc[j][r];
                yp[(size_t)r * F_] = v;
                csum[j] += v;
                csq[j] = fmaf(v, v, csq[j]);
            }
        }
    }
#pragma unroll
    for (int j = 0; j < 8; ++j) {
        float sm = csum[j], q = csq[j];
        sm += __shfl_xor(sm, 16); q += __shfl_xor(q, 16);
        sm += __shfl_xor(sm, 32); q += __shfl_xor(q, 32);
        if (l4 == 0) {
            atomicAdd(&s_sum[j * 16 + l15], sm);
            atomicAdd(&s_sq [j * 16 + l15], q);
        }
    }
    __syncthreads();
    if (tid < D_) {
        atomicAdd(&gsum[p * D_ + tid], s_sum[tid]);
        atomicAdd(&gsq [p * D_ + tid], s_sq[tid]);
    }
}

// -- K2: y3 = tanh(bn1(y1)) @ BD(W2) + x, in place over y1, fused stats3 ----
// Wave-private 16-row tiles: all reads of a tile are consumed before its
// in-place stores (program order) -> safe.
__global__ __launch_bounds__(512, 4) void k_gemm2(
    const float* __restrict__ x, float* __restrict__ yb /* y1 in, y3 out */,
    const float* __restrict__ W2,
    const float* __restrict__ sce, const float* __restrict__ she,
    float* __restrict__ gsum, float* __restrict__ gsq)
{
    __shared__ short s_w[D_ * D_];
    __shared__ float s_sc[D_], s_sh[D_];
    __shared__ float s_sum[D_], s_sq[D_];
    const int tid = threadIdx.x;
    const int p = blockIdx.x / STRIPS, strip = blockIdx.x % STRIPS;
    stage_w(W2 + (size_t)p * D_ * D_, s_w, tid);
    if (tid < D_) {
        s_sc[tid] = sce[p * D_ + tid];
        s_sh[tid] = she[p * D_ + tid];
        s_sum[tid] = 0.f; s_sq[tid] = 0.f;
    }
    __syncthreads();
    const int wave = tid >> 6, lane = tid & 63;
    const int l15 = lane & 15, l4 = lane >> 4;
    const int ldsb = lane * 16;

    float csum[8], csq[8];
#pragma unroll
    for (int j = 0; j < 8; ++j) { csum[j] = 0.f; csq[j] = 0.f; }

    for (int it = 0; it < ITERS; ++it) {
        const int row0 = strip * 512 + it * 128 + wave * 16;
        const float* ap = yb + (size_t)(row0 + l15) * F_ + p * D_ + l4 * 8;
        abuf a[4];
#pragma unroll
        for (int s = 0; s < 4; ++s) {
            const int kb = s * 32 + l4 * 8;
            f32x4 v0 = *(const f32x4*)(ap + s * 32);
            f32x4 v1 = *(const f32x4*)(ap + s * 32 + 4);
            f32x4 sc0 = *(const f32x4*)&s_sc[kb], sc1 = *(const f32x4*)&s_sc[kb + 4];
            f32x4 sh0 = *(const f32x4*)&s_sh[kb], sh1 = *(const f32x4*)&s_sh[kb + 4];
            float t0[4], t1[4];
#pragma unroll
            for (int q = 0; q < 4; ++q) {
                t0[q] = tanh_e(fmaf(v0[q], sc0[q], sh0[q]));
                t1[q] = tanh_e(fmaf(v1[q], sc1[q], sh1[q]));
            }
            a[s].u[0] = pk_bf16(t0[0], t0[1]);
            a[s].u[1] = pk_bf16(t0[2], t0[3]);
            a[s].u[2] = pk_bf16(t1[0], t1[1]);
            a[s].u[3] = pk_bf16(t1[2], t1[3]);
        }
        f32x4 acc[8];
#pragma unroll
        for (int j = 0; j < 8; ++j) acc[j] = (f32x4){0.f, 0.f, 0.f, 0.f};
#pragma unroll
        for (int s = 0; s < 4; ++s)
#pragma unroll
            for (int j = 0; j < 8; ++j) {
                s16x8 b = *(const s16x8*)((const char*)s_w + (j * 4 + s) * 1024 + ldsb);
                acc[j] = __builtin_amdgcn_mfma_f32_16x16x32_bf16(a[s].v, b, acc[j], 0, 0, 0);
            }
        // epilogue: + residual x, store y3 over y1, accumulate stats
        const int rb = row0 + l4 * 4;
#pragma unroll
        for (int j = 0; j < 8; ++j) {
            const size_t off = (size_t)rb * F_ + p * D_ + j * 16 + l15;
            const float* xp = x + off;
            float* yp = yb + off;
#pragma unroll
            for (int r = 0; r < 4; ++r) {
                float v = acc[j][r] + xp[(size_t)r * F_];
                yp[(size_t)r * F_] = v;
                csum[j] += v;
                csq[j] = fmaf(v, v, csq[j]);
            }
        }
    }
#pragma unroll
    for (int j = 0; j < 8; ++j) {
        float sm = csum[j], q = csq[j];
        sm += __shfl_xor(sm, 16); q += __shfl_xor(q, 16);
        sm += __shfl_xor(sm, 32); q += __shfl_xor(q, 32);
        if (l4 == 0) {
            atomicAdd(&s_sum[j * 16 + l15], sm);
            atomicAdd(&s_sq [j * 16 + l15], q);
        }
    }
    __syncthreads();
    if (tid < D_) {
        atomicAdd(&gsum[p * D_ + tid], s_sum[tid]);
        atomicAdd(&gsq [p * D_ + tid], s_sq[tid]);
    }
}

// --- BN finalize: scale/shift pre-multiplied by 2*log2(e) for tanh_e -------
__global__ void k_finalize(const float* __restrict__ sum,
                           const float* __restrict__ sumsq,
                           const float* __restrict__ gamma,
                           const float* __restrict__ beta,
                           float* __restrict__ sce, float* __restrict__ she)
{
    const float L2E2 = 2.f * 1.44269504088896340736f;
    int f = blockIdx.x * blockDim.x + threadIdx.x;
    if (f < F_) {
        float mean = sum[f] * (1.f / B_);
        float var  = sumsq[f] * (1.f / B_) - mean * mean;
        float rstd = rsqrtf(var + 1e-5f);
        float sc = gamma[f] * rstd;
        sce[f] = L2E2 * sc;
        she[f] = L2E2 * (beta[f] - mean * sc);
    }
}

// ----------- K3: o3 = tanh(bn3(y3)), in place on d_out ---------------------
__global__ void k_bn_tanh(float* yb, const float* __restrict__ sce,
                          const float* __restrict__ she)
{
    const size_t n4 = (size_t)B_ * F_ / 4;
    size_t i = (size_t)blockIdx.x * blockDim.x + threadIdx.x;
    const size_t stride = (size_t)gridDim.x * blockDim.x;
    for (; i < n4; i += stride) {
        f32x4 v = ((const f32x4*)yb)[i];
        int col = (int)((i * 4) & (F_ - 1));
        f32x4 sc = *(const f32x4*)(sce + col);
        f32x4 sh = *(const f32x4*)(she + col);
        f32x4 r;
#pragma unroll
        for (int t = 0; t < 4; ++t) r[t] = tanh_e(fmaf(v[t], sc[t], sh[t]));
        __builtin_nontemporal_store(r, (f32x4*)yb + i);
    }
}

extern "C" void kernel_launch(void* const* d_in, const int* in_sizes, int n_in,
                              void* d_out, int out_size, void* d_ws, size_t ws_size,
                              hipStream_t stream) {
    const float* x      = (const float*)d_in[0];
    const float* W1     = (const float*)d_in[1];
    // d_in[2] = bias1 (cancels inside BN1)
    const float* W2     = (const float*)d_in[3];
    // d_in[4] = bias2 (cancels inside BN3)
    const float* gamma1 = (const float*)d_in[5];
    const float* beta1  = (const float*)d_in[6];
    const float* gamma3 = (const float*)d_in[7];
    const float* beta3  = (const float*)d_in[8];

    float* yb = (float*)d_out;          // y1 -> y3 -> o3, all in d_out
    float* S  = (float*)d_ws;           // 128KB stats block
    float* sum1 = S;                    // zeroed
    float* sq1  = S + 4096;             // zeroed
    float* sum3 = S + 8192;             // zeroed
    float* sq3  = S + 12288;            // zeroed
    float* sce1 = S + 16384;
    float* she1 = S + 20480;
    float* sce3 = S + 24576;
    float* she3 = S + 28672;

    hipMemsetAsync(d_ws, 0, 4 * 4096 * sizeof(float), stream);

    k_gemm1<<<P_ * STRIPS, 512, 0, stream>>>(x, W1, yb, sum1, sq1);
    k_finalize<<<F_ / 256, 256, 0, stream>>>(sum1, sq1, gamma1, beta1, sce1, she1);
    k_gemm2<<<P_ * STRIPS, 512, 0, stream>>>(x, yb, W2, sce1, she1, sum3, sq3);
    k_finalize<<<F_ / 256, 256, 0, stream>>>(sum3, sq3, gamma3, beta3, sce3, she3);
    k_bn_tanh<<<8192, 256, 0, stream>>>(yb, sce3, she3);
}